// Round 5
// baseline (483.462 us; speedup 1.0000x reference)
//
#include <hip/hip_runtime.h>

#define LRES 128
#define HRES 1024
#define CB 16                 // cells per axis
#define NC (CB * CB * CB)     // 4096 cells
#define NBSORT 256            // blocks for hist/scatter
#define BTS 1024              // threads per hist/scatter block

static const int LVOX = LRES * LRES * LRES; // 2,097,152
static const int PPIX = HRES * HRES;        // 1,048,576
static const int TV = LVOX + 3 * PPIX;      // 5,242,880 transpose elems

typedef float f32x4 __attribute__((ext_vector_type(4)));
typedef unsigned u32x4 __attribute__((ext_vector_type(4)));

// ---------- helpers ----------

// Replicates reference _to_idx exactly.
__device__ __forceinline__ void to_idx(float c, int size, int& i0, int& i1, float& w) {
    float p = (c + 1.0f) * 0.5f * (float)(size - 1);
    float f = floorf(p);
    w = p - f;
    int i = (int)f;
    i0 = min(max(i, 0), size - 1);
    i1 = min(i0 + 1, size - 1);
}

// float -> bf16 (RNE)
__device__ __forceinline__ unsigned f2bf(float f) {
    unsigned u = __float_as_uint(f);
    return (u + 0x7FFFu + ((u >> 16) & 1u)) >> 16;
}
__device__ __forceinline__ float bflo(unsigned u) { return __uint_as_float(u << 16); }
__device__ __forceinline__ float bfhi(unsigned u) { return __uint_as_float(u & 0xFFFF0000u); }

__device__ __forceinline__ void fma8u(f32x4& a0, f32x4& a1, uint4 q, float w) {
    a0.x = fmaf(bflo(q.x), w, a0.x);
    a0.y = fmaf(bfhi(q.x), w, a0.y);
    a0.z = fmaf(bflo(q.y), w, a0.z);
    a0.w = fmaf(bfhi(q.y), w, a0.w);
    a1.x = fmaf(bflo(q.z), w, a1.x);
    a1.y = fmaf(bfhi(q.z), w, a1.y);
    a1.z = fmaf(bflo(q.w), w, a1.z);
    a1.w = fmaf(bfhi(q.w), w, a1.w);
}

__device__ __forceinline__ unsigned spread3(unsigned x) {
    x &= 0x3FFu;
    x = (x | (x << 16)) & 0x030000FFu;
    x = (x | (x << 8)) & 0x0300F00Fu;
    x = (x | (x << 4)) & 0x030C30C3u;
    x = (x | (x << 2)) & 0x09249249u;
    return x;
}
// Morton cell id on a 16^3 lattice
__device__ __forceinline__ unsigned cell16(float x, float y, float z) {
    int cx = min(max((int)(x * (float)CB), 0), CB - 1);
    int cy = min(max((int)(y * (float)CB), 0), CB - 1);
    int cz = min(max((int)(z * (float)CB), 0), CB - 1);
    return spread3(cx) | (spread3(cy) << 1) | (spread3(cz) << 2);
}

// ---------- fused prep: blocks [0,NBSORT) = LDS histogram, rest = transpose ----------
// histmat layout is CELL-MAJOR: histmat[c * NBSORT + b].
__global__ __launch_bounds__(BTS) void prep_k(const float* __restrict__ xyz,
                                              const int* __restrict__ boundp,
                                              const float* __restrict__ Lg,
                                              const float* __restrict__ Hp,
                                              unsigned* __restrict__ histmat,
                                              u32x4* __restrict__ gclb,
                                              u32x4* __restrict__ pclb, int N) {
    __shared__ unsigned h[NC];
    int b = blockIdx.x;
    if (b < NBSORT) {
        // ---- histogram part ----
        for (int i = threadIdx.x; i < NC; i += BTS) h[i] = 0u;
        __syncthreads();
        float invb = 1.0f / (float)boundp[0];
        for (int n = b * BTS + threadIdx.x; n < N; n += NBSORT * BTS) {
            float x = xyz[(size_t)3 * n + 0] * invb;
            float y = xyz[(size_t)3 * n + 1] * invb;
            float z = xyz[(size_t)3 * n + 2] * invb;
            atomicAdd(&h[cell16(x, y, z)], 1u);
        }
        __syncthreads();
        for (int i = threadIdx.x; i < NC; i += BTS)
            histmat[(size_t)i * NBSORT + b] = h[i];
    } else {
        // ---- transpose part: one channels-last bf16 element per thread ----
        int v = (b - NBSORT) * BTS + threadIdx.x;
        if (v >= TV) return;
        unsigned hh[8];
        u32x4* dst;
        if (v < LVOX) {
#pragma unroll
            for (int c = 0; c < 8; ++c) hh[c] = f2bf(Lg[(size_t)c * LVOX + v]);
            dst = gclb + v;
        } else {
            int u = v - LVOX;
            int p = u >> 20;          // / PPIX
            int r = u & (PPIX - 1);   // % PPIX
            const float* src = Hp + (size_t)p * 8 * PPIX;
#pragma unroll
            for (int c = 0; c < 8; ++c) hh[c] = f2bf(src[(size_t)c * PPIX + r]);
            dst = pclb + (size_t)p * PPIX + r;
        }
        u32x4 o;
        o.x = hh[0] | (hh[1] << 16);
        o.y = hh[2] | (hh[3] << 16);
        o.z = hh[4] | (hh[5] << 16);
        o.w = hh[6] | (hh[7] << 16);
        __builtin_nontemporal_store(o, dst);
    }
}

// Per-cell exclusive prefix across blocks (cell-major: contiguous 256 entries).
__global__ __launch_bounds__(256) void rowpref(unsigned* __restrict__ histmat,
                                               unsigned* __restrict__ total) {
    int c = blockIdx.x * 256 + threadIdx.x; // 0..NC-1
    u32x4* row = (u32x4*)(histmat + (size_t)c * NBSORT);
    unsigned run = 0;
#pragma unroll 4
    for (int k = 0; k < NBSORT / 4; ++k) {
        u32x4 v = row[k];
        unsigned t;
        t = v.x; v.x = run; run += t;
        t = v.y; v.y = run; run += t;
        t = v.z; v.z = run; run += t;
        t = v.w; v.w = run; run += t;
        row[k] = v;
    }
    total[c] = run;
}

// Exclusive scan of NC totals -> cellbase. One block, 1024 threads, 4 elems each.
__global__ __launch_bounds__(1024) void scan2_k(const unsigned* __restrict__ total,
                                                unsigned* __restrict__ cellbase) {
    __shared__ unsigned s[1024];
    int tid = threadIdx.x;
    unsigned v[4];
    unsigned sum = 0;
#pragma unroll
    for (int k = 0; k < 4; ++k) {
        v[k] = total[tid * 4 + k];
        sum += v[k];
    }
    s[tid] = sum;
    __syncthreads();
    for (int o = 1; o < 1024; o <<= 1) {
        unsigned t = (tid >= o) ? s[tid - o] : 0u;
        __syncthreads();
        s[tid] += t;
        __syncthreads();
    }
    unsigned base = s[tid] - sum; // exclusive
#pragma unroll
    for (int k = 0; k < 4; ++k) {
        cellbase[tid * 4 + k] = base;
        base += v[k];
    }
}

// Scatter: block b seeds LDS counters with cellbase[c] + histmat[c][b], then
// ranks its points via LDS atomics.
__global__ __launch_bounds__(BTS) void scatter_pb(const float* __restrict__ xyz,
                                                  const int* __restrict__ boundp,
                                                  const unsigned* __restrict__ histmat,
                                                  const unsigned* __restrict__ cellbase,
                                                  float4* __restrict__ sorted, int N) {
    __shared__ unsigned cnt[NC];
    int b = blockIdx.x;
    for (int i = threadIdx.x; i < NC; i += BTS)
        cnt[i] = cellbase[i] + histmat[(size_t)i * NBSORT + b];
    __syncthreads();
    float invb = 1.0f / (float)boundp[0];
    for (int n = b * BTS + threadIdx.x; n < N; n += NBSORT * BTS) {
        float x = xyz[(size_t)3 * n + 0] * invb;
        float y = xyz[(size_t)3 * n + 1] * invb;
        float z = xyz[(size_t)3 * n + 2] * invb;
        unsigned c = cell16(x, y, z);
        unsigned d = atomicAdd(&cnt[c], 1u);
        sorted[d] = make_float4(x, y, z, __int_as_float(n));
    }
}

// ---------- main sampler (sorted order, bf16 channels-last tables) ----------
__global__ __launch_bounds__(256) void sample_srt(const f32x4* __restrict__ sorted,
                                                  const uint4* __restrict__ gclb,
                                                  const uint4* __restrict__ pclb,
                                                  float* __restrict__ out, int N) {
    int i = blockIdx.x * blockDim.x + threadIdx.x;
    if (i >= N) return;
    f32x4 rec = __builtin_nontemporal_load(sorted + i);
    float x = rec.x, y = rec.y, z = rec.z;
    int idx = __float_as_int(rec.w);

    // --- grid indices + issue all 8 grid loads ---
    int x0, x1, y0, y1, z0, z1;
    float wx, wy, wz;
    to_idx(x, LRES, x0, x1, wx);
    to_idx(y, LRES, y0, y1, wy);
    to_idx(z, LRES, z0, z1, wz);
    const uint4* b00 = gclb + ((size_t)z0 * LRES + y0) * LRES;
    const uint4* b01 = gclb + ((size_t)z0 * LRES + y1) * LRES;
    const uint4* b10 = gclb + ((size_t)z1 * LRES + y0) * LRES;
    const uint4* b11 = gclb + ((size_t)z1 * LRES + y1) * LRES;
    uint4 g0 = b00[x0], g1 = b00[x1], g2 = b01[x0], g3 = b01[x1];
    uint4 g4 = b10[x0], g5 = b10[x1], g6 = b11[x0], g7 = b11[x1];

    // --- plane indices + issue all 12 plane loads ---
    const float cw[3] = {x, y, z};
    const float ch[3] = {y, z, x};
    float pww[3], pwh[3];
    uint4 r[12];
#pragma unroll
    for (int p = 0; p < 3; ++p) {
        int w0, w1, h0, h1;
        to_idx(cw[p], HRES, w0, w1, pww[p]);
        to_idx(ch[p], HRES, h0, h1, pwh[p]);
        const uint4* base = pclb + (size_t)p * PPIX;
        const uint4* r0 = base + (size_t)h0 * HRES;
        const uint4* r1 = base + (size_t)h1 * HRES;
        r[4 * p + 0] = r0[w0];
        r[4 * p + 1] = r0[w1];
        r[4 * p + 2] = r1[w0];
        r[4 * p + 3] = r1[w1];
    }

    // --- FMAs ---
    f32x4 a0 = (f32x4)0.f;
    f32x4 a1 = (f32x4)0.f;
    {
        float ux = 1.f - wx, uy = 1.f - wy, uz = 1.f - wz;
        fma8u(a0, a1, g0, uz * uy * ux);
        fma8u(a0, a1, g1, uz * uy * wx);
        fma8u(a0, a1, g2, uz * wy * ux);
        fma8u(a0, a1, g3, uz * wy * wx);
        fma8u(a0, a1, g4, wz * uy * ux);
        fma8u(a0, a1, g5, wz * uy * wx);
        fma8u(a0, a1, g6, wz * wy * ux);
        fma8u(a0, a1, g7, wz * wy * wx);
    }
#pragma unroll
    for (int p = 0; p < 3; ++p) {
        float ww = pww[p], wh = pwh[p];
        float uw = 1.f - ww, uh = 1.f - wh;
        fma8u(a0, a1, r[4 * p + 0], uh * uw);
        fma8u(a0, a1, r[4 * p + 1], uh * ww);
        fma8u(a0, a1, r[4 * p + 2], wh * uw);
        fma8u(a0, a1, r[4 * p + 3], wh * ww);
    }

    f32x4* o = (f32x4*)(out + (size_t)idx * 8);
    __builtin_nontemporal_store(a0, o);
    __builtin_nontemporal_store(a1, o + 1);
}

// ---------- fallback (channel-first fp32 direct, known-correct) ----------
__global__ __launch_bounds__(256) void sample_cf(
    const float* __restrict__ xyz, const int* __restrict__ boundp,
    const float* __restrict__ Lg, const float* __restrict__ Hp,
    float* __restrict__ out, int N) {
    int n = blockIdx.x * blockDim.x + threadIdx.x;
    if (n >= N) return;
    float invb = 1.0f / (float)boundp[0];
    float x = xyz[(size_t)3 * n + 0] * invb;
    float y = xyz[(size_t)3 * n + 1] * invb;
    float z = xyz[(size_t)3 * n + 2] * invb;
    float acc[8];
#pragma unroll
    for (int c = 0; c < 8; ++c) acc[c] = 0.f;
    {
        int x0, x1, y0, y1, z0, z1;
        float wx, wy, wz;
        to_idx(x, LRES, x0, x1, wx);
        to_idx(y, LRES, y0, y1, wy);
        to_idx(z, LRES, z0, z1, wz);
        float ux = 1.f - wx, uy = 1.f - wy, uz = 1.f - wz;
        size_t i8[8];
        i8[0] = ((size_t)z0 * LRES + y0) * LRES + x0;
        i8[1] = ((size_t)z0 * LRES + y0) * LRES + x1;
        i8[2] = ((size_t)z0 * LRES + y1) * LRES + x0;
        i8[3] = ((size_t)z0 * LRES + y1) * LRES + x1;
        i8[4] = ((size_t)z1 * LRES + y0) * LRES + x0;
        i8[5] = ((size_t)z1 * LRES + y0) * LRES + x1;
        i8[6] = ((size_t)z1 * LRES + y1) * LRES + x0;
        i8[7] = ((size_t)z1 * LRES + y1) * LRES + x1;
        float w8[8] = {uz * uy * ux, uz * uy * wx, uz * wy * ux, uz * wy * wx,
                       wz * uy * ux, wz * uy * wx, wz * wy * ux, wz * wy * wx};
#pragma unroll
        for (int c = 0; c < 8; ++c) {
            const float* g = Lg + (size_t)c * LVOX;
            float s = 0.f;
#pragma unroll
            for (int k = 0; k < 8; ++k) s = fmaf(g[i8[k]], w8[k], s);
            acc[c] += s;
        }
    }
    {
        const float cw[3] = {x, y, z};
        const float ch[3] = {y, z, x};
        for (int p = 0; p < 3; ++p) {
            int w0, w1, h0, h1;
            float ww, wh;
            to_idx(cw[p], HRES, w0, w1, ww);
            to_idx(ch[p], HRES, h0, h1, wh);
            float uw = 1.f - ww, uh = 1.f - wh;
            size_t i4[4] = {(size_t)h0 * HRES + w0, (size_t)h0 * HRES + w1,
                            (size_t)h1 * HRES + w0, (size_t)h1 * HRES + w1};
            float w4[4] = {uh * uw, uh * ww, wh * uw, wh * ww};
            const float* pb = Hp + (size_t)p * 8 * PPIX;
#pragma unroll
            for (int c = 0; c < 8; ++c) {
                const float* g = pb + (size_t)c * PPIX;
                float s = 0.f;
#pragma unroll
                for (int k = 0; k < 4; ++k) s = fmaf(g[i4[k]], w4[k], s);
                acc[c] += s;
            }
        }
    }
#pragma unroll
    for (int c = 0; c < 8; ++c) out[(size_t)n * 8 + c] = acc[c];
}

extern "C" void kernel_launch(void* const* d_in, const int* in_sizes, int n_in,
                              void* d_out, int out_size, void* d_ws, size_t ws_size,
                              hipStream_t stream) {
    const float* xyz = (const float*)d_in[0];
    const int* bound = (const int*)d_in[1];
    const float* Lg = (const float*)d_in[2]; // [8,128,128,128]
    const float* Hp = (const float*)d_in[3]; // [3,8,1024,1024]
    float* out = (float*)d_out;
    int N = in_sizes[0] / 3;

    // workspace layout (bytes)
    size_t off = 0;
    size_t gclb_b = (size_t)LVOX * 16;       // 32 MiB
    size_t pclb_b = (size_t)3 * PPIX * 16;   // 48 MiB
    size_t sort_b = (size_t)N * 16;          // 32 MB
    size_t hmat_b = (size_t)NC * NBSORT * 4; // 4 MiB
    size_t tot_b = (size_t)NC * 4;           // 16 KiB
    size_t cb_b = (size_t)NC * 4;            // 16 KiB
    size_t need = gclb_b + pclb_b + sort_b + hmat_b + tot_b + cb_b;

    if (ws_size >= need) {
        char* w = (char*)d_ws;
        u32x4* gclb = (u32x4*)(w + off);        off += gclb_b;
        u32x4* pclb = (u32x4*)(w + off);        off += pclb_b;
        float4* sorted = (float4*)(w + off);    off += sort_b;
        unsigned* hmat = (unsigned*)(w + off);  off += hmat_b;
        unsigned* total = (unsigned*)(w + off); off += tot_b;
        unsigned* cbase = (unsigned*)(w + off);

        int prep_blocks = NBSORT + (TV + BTS - 1) / BTS; // 256 + 5120
        prep_k<<<prep_blocks, BTS, 0, stream>>>(xyz, bound, Lg, Hp, hmat, gclb, pclb, N);
        rowpref<<<NC / 256, 256, 0, stream>>>(hmat, total);
        scan2_k<<<1, 1024, 0, stream>>>(total, cbase);
        scatter_pb<<<NBSORT, BTS, 0, stream>>>(xyz, bound, hmat, cbase, sorted, N);
        sample_srt<<<(N + 255) / 256, 256, 0, stream>>>((const f32x4*)sorted,
                                                        (const uint4*)gclb,
                                                        (const uint4*)pclb, out, N);
    } else {
        sample_cf<<<(N + 255) / 256, 256, 0, stream>>>(xyz, bound, Lg, Hp, out, N);
    }
}

// Round 6
// 406.466 us; speedup vs baseline: 1.1894x; 1.1894x over previous
//
#include <hip/hip_runtime.h>

#define LRES 128
#define HRES 1024
#define NB 256        // hist/scatter blocks
#define BTS 1024      // threads for big blocks
#define NBUCK 512     // coarse buckets (Morton top 9 bits of 128^3 lattice)
#define RCAP 8192     // refine in-register cap per bucket (avg ~3906)

static const int LVOX = LRES * LRES * LRES; // 2,097,152
static const int PPIX = HRES * HRES;        // 1,048,576
static const int TV = LVOX + 3 * PPIX;      // 5,242,880 transpose elems

typedef float f32x4 __attribute__((ext_vector_type(4)));
typedef unsigned u32x4 __attribute__((ext_vector_type(4)));

// ---------- helpers ----------

// Replicates reference _to_idx exactly.
__device__ __forceinline__ void to_idx(float c, int size, int& i0, int& i1, float& w) {
    float p = (c + 1.0f) * 0.5f * (float)(size - 1);
    float f = floorf(p);
    w = p - f;
    int i = (int)f;
    i0 = min(max(i, 0), size - 1);
    i1 = min(i0 + 1, size - 1);
}

// float -> bf16 (RNE)
__device__ __forceinline__ unsigned f2bf(float f) {
    unsigned u = __float_as_uint(f);
    return (u + 0x7FFFu + ((u >> 16) & 1u)) >> 16;
}
__device__ __forceinline__ float bflo(unsigned u) { return __uint_as_float(u << 16); }
__device__ __forceinline__ float bfhi(unsigned u) { return __uint_as_float(u & 0xFFFF0000u); }

__device__ __forceinline__ void fma8u(f32x4& a0, f32x4& a1, uint4 q, float w) {
    a0.x = fmaf(bflo(q.x), w, a0.x);
    a0.y = fmaf(bfhi(q.x), w, a0.y);
    a0.z = fmaf(bflo(q.y), w, a0.z);
    a0.w = fmaf(bfhi(q.y), w, a0.w);
    a1.x = fmaf(bflo(q.z), w, a1.x);
    a1.y = fmaf(bfhi(q.z), w, a1.y);
    a1.z = fmaf(bflo(q.w), w, a1.z);
    a1.w = fmaf(bfhi(q.w), w, a1.w);
}

__device__ __forceinline__ unsigned spread3(unsigned x) {
    x &= 0x3FFu;
    x = (x | (x << 16)) & 0x030000FFu;
    x = (x | (x << 8)) & 0x0300F00Fu;
    x = (x | (x << 4)) & 0x030C30C3u;
    x = (x | (x << 2)) & 0x09249249u;
    return x;
}
// 21-bit Morton on a 128^3 lattice over [0,1)^3. bucket = >>12, fine = &4095.
__device__ __forceinline__ unsigned morton21(float x, float y, float z) {
    int px = min(max((int)(x * 128.f), 0), 127);
    int py = min(max((int)(y * 128.f), 0), 127);
    int pz = min(max((int)(z * 128.f), 0), 127);
    return spread3(px) | (spread3(py) << 1) | (spread3(pz) << 2);
}

// ---------- fused prep: blocks [0,NB) = bucket histogram, rest = transpose ----------
// hmat is BLOCK-major: hmat[b * NBUCK + c].
__global__ __launch_bounds__(BTS) void prep_k(const float* __restrict__ xyz,
                                              const int* __restrict__ boundp,
                                              const float* __restrict__ Lg,
                                              const float* __restrict__ Hp,
                                              unsigned* __restrict__ hmat,
                                              u32x4* __restrict__ gclb,
                                              u32x4* __restrict__ pclb, int N) {
    __shared__ unsigned h[NBUCK];
    int b = blockIdx.x;
    if (b < NB) {
        for (int i = threadIdx.x; i < NBUCK; i += BTS) h[i] = 0u;
        __syncthreads();
        float invb = 1.0f / (float)boundp[0];
        for (int n = b * BTS + threadIdx.x; n < N; n += NB * BTS) {
            float x = xyz[(size_t)3 * n + 0] * invb;
            float y = xyz[(size_t)3 * n + 1] * invb;
            float z = xyz[(size_t)3 * n + 2] * invb;
            atomicAdd(&h[morton21(x, y, z) >> 12], 1u);
        }
        __syncthreads();
        for (int i = threadIdx.x; i < NBUCK; i += BTS)
            hmat[(size_t)b * NBUCK + i] = h[i];
    } else {
        // transpose: two channels-last bf16 elements per thread
        int v = ((b - NB) * BTS + threadIdx.x) * 2;
        if (v >= TV) return;
        unsigned ha[8], hb[8];
        u32x4* dst;
        if (v < LVOX) {
#pragma unroll
            for (int c = 0; c < 8; ++c) {
                float2 f = *(const float2*)(Lg + (size_t)c * LVOX + v);
                ha[c] = f2bf(f.x);
                hb[c] = f2bf(f.y);
            }
            dst = gclb + v;
        } else {
            int u = v - LVOX;
            int p = u >> 20;
            int r = u & (PPIX - 1);
            const float* src = Hp + (size_t)p * 8 * PPIX;
#pragma unroll
            for (int c = 0; c < 8; ++c) {
                float2 f = *(const float2*)(src + (size_t)c * PPIX + r);
                ha[c] = f2bf(f.x);
                hb[c] = f2bf(f.y);
            }
            dst = pclb + (size_t)p * PPIX + r;
        }
        u32x4 o1, o2;
        o1.x = ha[0] | (ha[1] << 16); o1.y = ha[2] | (ha[3] << 16);
        o1.z = ha[4] | (ha[5] << 16); o1.w = ha[6] | (ha[7] << 16);
        o2.x = hb[0] | (hb[1] << 16); o2.y = hb[2] | (hb[3] << 16);
        o2.z = hb[4] | (hb[5] << 16); o2.w = hb[6] | (hb[7] << 16);
        __builtin_nontemporal_store(o1, dst);
        __builtin_nontemporal_store(o2, dst + 1);
    }
}

// Single block: cross-block prefix per bucket (in place), scan bucket totals,
// emit bucket_base[NBUCK+1], add base into hmat (seed for scatter).
__global__ __launch_bounds__(1024) void offsets_k(unsigned* __restrict__ hmat,
                                                  unsigned* __restrict__ bb) {
    __shared__ unsigned tot[NBUCK];
    __shared__ unsigned cbase[NBUCK];
    int t = threadIdx.x;
    unsigned run = 0;
    if (t < NBUCK) {
        for (int b = 0; b < NB; ++b) {
            unsigned v = hmat[(size_t)b * NBUCK + t];
            hmat[(size_t)b * NBUCK + t] = run;
            run += v;
        }
        tot[t] = run;
    }
    __syncthreads();
    for (int o = 1; o < NBUCK; o <<= 1) {
        unsigned v = 0;
        if (t < NBUCK && t >= o) v = tot[t - o];
        __syncthreads();
        if (t < NBUCK) tot[t] += v;
        __syncthreads();
    }
    if (t < NBUCK) {
        unsigned excl = tot[t] - run;
        cbase[t] = excl;
        bb[t] = excl;
        if (t == NBUCK - 1) bb[NBUCK] = tot[t];
    }
    __syncthreads();
    for (int idx = t; idx < NB * NBUCK; idx += 1024)
        hmat[idx] += cbase[idx & (NBUCK - 1)];
}

// Scatter into 512-bucket order: long destination runs (~15 pts) -> good lines.
__global__ __launch_bounds__(BTS) void scatter_k(const float* __restrict__ xyz,
                                                 const int* __restrict__ boundp,
                                                 const unsigned* __restrict__ hmat,
                                                 float4* __restrict__ s1, int N) {
    __shared__ unsigned cnt[NBUCK];
    int b = blockIdx.x;
    for (int i = threadIdx.x; i < NBUCK; i += BTS)
        cnt[i] = hmat[(size_t)b * NBUCK + i];
    __syncthreads();
    float invb = 1.0f / (float)boundp[0];
    for (int n = b * BTS + threadIdx.x; n < N; n += NB * BTS) {
        float x = xyz[(size_t)3 * n + 0] * invb;
        float y = xyz[(size_t)3 * n + 1] * invb;
        float z = xyz[(size_t)3 * n + 2] * invb;
        unsigned key = morton21(x, y, z) >> 12;
        unsigned d = atomicAdd(&cnt[key], 1u);
        s1[d] = make_float4(x, y, z, __int_as_float(n));
    }
}

// Per-bucket LDS counting sort by fine 12-bit Morton key -> full 128^3 order.
// Records live in registers; LDS only holds the 4096 counters + scan aux.
__global__ __launch_bounds__(1024) void refine_k(const float4* __restrict__ s1,
                                                 const unsigned* __restrict__ bb,
                                                 float4* __restrict__ s2) {
    __shared__ unsigned hist[4096];
    __shared__ unsigned part[1024];
    int b = blockIdx.x;
    unsigned start = bb[b];
    unsigned cnt = bb[b + 1] - start;
    int t = threadIdx.x;
    if (cnt > RCAP) { // statistically unreachable; correctness fallback
        for (unsigned j = t; j < cnt; j += 1024) s2[start + j] = s1[start + j];
        return;
    }
    for (int i = t; i < 4096; i += 1024) hist[i] = 0u;
    __syncthreads();
    float4 rec[RCAP / 1024];
    unsigned key[RCAP / 1024], tick[RCAP / 1024];
#pragma unroll
    for (int k = 0; k < RCAP / 1024; ++k) {
        unsigned j = t + k * 1024u;
        if (j < cnt) {
            rec[k] = s1[start + j];
            key[k] = morton21(rec[k].x, rec[k].y, rec[k].z) & 4095u;
            tick[k] = atomicAdd(&hist[key[k]], 1u);
        }
    }
    __syncthreads();
    unsigned h4[4];
    unsigned s = 0;
#pragma unroll
    for (int k = 0; k < 4; ++k) {
        h4[k] = hist[t * 4 + k];
        s += h4[k];
    }
    part[t] = s;
    __syncthreads();
    for (int o = 1; o < 1024; o <<= 1) {
        unsigned v = (t >= o) ? part[t - o] : 0u;
        __syncthreads();
        part[t] += v;
        __syncthreads();
    }
    unsigned base = part[t] - s;
#pragma unroll
    for (int k = 0; k < 4; ++k) {
        hist[t * 4 + k] = base;
        base += h4[k];
    }
    __syncthreads();
#pragma unroll
    for (int k = 0; k < RCAP / 1024; ++k) {
        unsigned j = t + k * 1024u;
        if (j < cnt) s2[start + hist[key[k]] + tick[k]] = rec[k];
    }
}

// ---------- main sampler (Morton order, bf16 channels-last tables) ----------
__global__ __launch_bounds__(256) void sample_srt(const float4* __restrict__ sorted,
                                                  const uint4* __restrict__ gclb,
                                                  const uint4* __restrict__ pclb,
                                                  float* __restrict__ out, int N) {
    int i = blockIdx.x * blockDim.x + threadIdx.x;
    if (i >= N) return;
    float4 rec = sorted[i];
    float x = rec.x, y = rec.y, z = rec.z;
    int idx = __float_as_int(rec.w);

    int x0, x1, y0, y1, z0, z1;
    float wx, wy, wz;
    to_idx(x, LRES, x0, x1, wx);
    to_idx(y, LRES, y0, y1, wy);
    to_idx(z, LRES, z0, z1, wz);
    const uint4* b00 = gclb + ((size_t)z0 * LRES + y0) * LRES;
    const uint4* b01 = gclb + ((size_t)z0 * LRES + y1) * LRES;
    const uint4* b10 = gclb + ((size_t)z1 * LRES + y0) * LRES;
    const uint4* b11 = gclb + ((size_t)z1 * LRES + y1) * LRES;
    uint4 g0 = b00[x0], g1 = b00[x1], g2 = b01[x0], g3 = b01[x1];
    uint4 g4 = b10[x0], g5 = b10[x1], g6 = b11[x0], g7 = b11[x1];

    const float cw[3] = {x, y, z};
    const float ch[3] = {y, z, x};
    float pww[3], pwh[3];
    uint4 r[12];
#pragma unroll
    for (int p = 0; p < 3; ++p) {
        int w0, w1, h0, h1;
        to_idx(cw[p], HRES, w0, w1, pww[p]);
        to_idx(ch[p], HRES, h0, h1, pwh[p]);
        const uint4* base = pclb + (size_t)p * PPIX;
        const uint4* r0 = base + (size_t)h0 * HRES;
        const uint4* r1 = base + (size_t)h1 * HRES;
        r[4 * p + 0] = r0[w0];
        r[4 * p + 1] = r0[w1];
        r[4 * p + 2] = r1[w0];
        r[4 * p + 3] = r1[w1];
    }

    f32x4 a0 = (f32x4)0.f;
    f32x4 a1 = (f32x4)0.f;
    {
        float ux = 1.f - wx, uy = 1.f - wy, uz = 1.f - wz;
        fma8u(a0, a1, g0, uz * uy * ux);
        fma8u(a0, a1, g1, uz * uy * wx);
        fma8u(a0, a1, g2, uz * wy * ux);
        fma8u(a0, a1, g3, uz * wy * wx);
        fma8u(a0, a1, g4, wz * uy * ux);
        fma8u(a0, a1, g5, wz * uy * wx);
        fma8u(a0, a1, g6, wz * wy * ux);
        fma8u(a0, a1, g7, wz * wy * wx);
    }
#pragma unroll
    for (int p = 0; p < 3; ++p) {
        float ww = pww[p], wh = pwh[p];
        float uw = 1.f - ww, uh = 1.f - wh;
        fma8u(a0, a1, r[4 * p + 0], uh * uw);
        fma8u(a0, a1, r[4 * p + 1], uh * ww);
        fma8u(a0, a1, r[4 * p + 2], wh * uw);
        fma8u(a0, a1, r[4 * p + 3], wh * ww);
    }

    f32x4* o = (f32x4*)(out + (size_t)idx * 8);
    o[0] = a0;
    o[1] = a1;
}

// ---------- fallback (channel-first fp32 direct, known-correct) ----------
__global__ __launch_bounds__(256) void sample_cf(
    const float* __restrict__ xyz, const int* __restrict__ boundp,
    const float* __restrict__ Lg, const float* __restrict__ Hp,
    float* __restrict__ out, int N) {
    int n = blockIdx.x * blockDim.x + threadIdx.x;
    if (n >= N) return;
    float invb = 1.0f / (float)boundp[0];
    float x = xyz[(size_t)3 * n + 0] * invb;
    float y = xyz[(size_t)3 * n + 1] * invb;
    float z = xyz[(size_t)3 * n + 2] * invb;
    float acc[8];
#pragma unroll
    for (int c = 0; c < 8; ++c) acc[c] = 0.f;
    {
        int x0, x1, y0, y1, z0, z1;
        float wx, wy, wz;
        to_idx(x, LRES, x0, x1, wx);
        to_idx(y, LRES, y0, y1, wy);
        to_idx(z, LRES, z0, z1, wz);
        float ux = 1.f - wx, uy = 1.f - wy, uz = 1.f - wz;
        size_t i8[8];
        i8[0] = ((size_t)z0 * LRES + y0) * LRES + x0;
        i8[1] = ((size_t)z0 * LRES + y0) * LRES + x1;
        i8[2] = ((size_t)z0 * LRES + y1) * LRES + x0;
        i8[3] = ((size_t)z0 * LRES + y1) * LRES + x1;
        i8[4] = ((size_t)z1 * LRES + y0) * LRES + x0;
        i8[5] = ((size_t)z1 * LRES + y0) * LRES + x1;
        i8[6] = ((size_t)z1 * LRES + y1) * LRES + x0;
        i8[7] = ((size_t)z1 * LRES + y1) * LRES + x1;
        float w8[8] = {uz * uy * ux, uz * uy * wx, uz * wy * ux, uz * wy * wx,
                       wz * uy * ux, wz * uy * wx, wz * wy * ux, wz * wy * wx};
#pragma unroll
        for (int c = 0; c < 8; ++c) {
            const float* g = Lg + (size_t)c * LVOX;
            float s = 0.f;
#pragma unroll
            for (int k = 0; k < 8; ++k) s = fmaf(g[i8[k]], w8[k], s);
            acc[c] += s;
        }
    }
    {
        const float cw[3] = {x, y, z};
        const float ch[3] = {y, z, x};
        for (int p = 0; p < 3; ++p) {
            int w0, w1, h0, h1;
            float ww, wh;
            to_idx(cw[p], HRES, w0, w1, ww);
            to_idx(ch[p], HRES, h0, h1, wh);
            float uw = 1.f - ww, uh = 1.f - wh;
            size_t i4[4] = {(size_t)h0 * HRES + w0, (size_t)h0 * HRES + w1,
                            (size_t)h1 * HRES + w0, (size_t)h1 * HRES + w1};
            float w4[4] = {uh * uw, uh * ww, wh * uw, wh * ww};
            const float* pb = Hp + (size_t)p * 8 * PPIX;
#pragma unroll
            for (int c = 0; c < 8; ++c) {
                const float* g = pb + (size_t)c * PPIX;
                float s = 0.f;
#pragma unroll
                for (int k = 0; k < 4; ++k) s = fmaf(g[i4[k]], w4[k], s);
                acc[c] += s;
            }
        }
    }
#pragma unroll
    for (int c = 0; c < 8; ++c) out[(size_t)n * 8 + c] = acc[c];
}

extern "C" void kernel_launch(void* const* d_in, const int* in_sizes, int n_in,
                              void* d_out, int out_size, void* d_ws, size_t ws_size,
                              hipStream_t stream) {
    const float* xyz = (const float*)d_in[0];
    const int* bound = (const int*)d_in[1];
    const float* Lg = (const float*)d_in[2]; // [8,128,128,128]
    const float* Hp = (const float*)d_in[3]; // [3,8,1024,1024]
    float* out = (float*)d_out;
    int N = in_sizes[0] / 3;

    size_t off = 0;
    size_t gclb_b = (size_t)LVOX * 16;         // 32 MiB
    size_t pclb_b = (size_t)3 * PPIX * 16;     // 48 MiB
    size_t s1_b = (size_t)N * 16;              // 32 MB
    size_t s2_b = (size_t)N * 16;              // 32 MB
    size_t hmat_b = (size_t)NB * NBUCK * 4;    // 512 KiB
    size_t bb_b = (size_t)(NBUCK + 1) * 4;
    size_t need = gclb_b + pclb_b + s1_b + s2_b + hmat_b + bb_b;

    if (ws_size >= need) {
        char* w = (char*)d_ws;
        u32x4* gclb = (u32x4*)(w + off);       off += gclb_b;
        u32x4* pclb = (u32x4*)(w + off);       off += pclb_b;
        float4* s1 = (float4*)(w + off);       off += s1_b;
        float4* s2 = (float4*)(w + off);       off += s2_b;
        unsigned* hmat = (unsigned*)(w + off); off += hmat_b;
        unsigned* bb = (unsigned*)(w + off);

        int prep_blocks = NB + (TV / 2 + BTS - 1) / BTS; // 256 + 2560
        prep_k<<<prep_blocks, BTS, 0, stream>>>(xyz, bound, Lg, Hp, hmat, gclb, pclb, N);
        offsets_k<<<1, 1024, 0, stream>>>(hmat, bb);
        scatter_k<<<NB, BTS, 0, stream>>>(xyz, bound, hmat, s1, N);
        refine_k<<<NBUCK, 1024, 0, stream>>>(s1, bb, s2);
        sample_srt<<<(N + 255) / 256, 256, 0, stream>>>(s2, (const uint4*)gclb,
                                                        (const uint4*)pclb, out, N);
    } else {
        sample_cf<<<(N + 255) / 256, 256, 0, stream>>>(xyz, bound, Lg, Hp, out, N);
    }
}